// Round 4
// baseline (489.087 us; speedup 1.0000x reference)
//
#include <hip/hip_runtime.h>

#define B_N 8192
#define D_N 512
#define K_N 64
#define H_N 256
#define SC  4608   // K*K + D
#define R_T 16     // rows per tile/block
#define NT  512    // 8 waves

typedef __attribute__((ext_vector_type(8))) short short8;
typedef __attribute__((ext_vector_type(4))) short short4v;
typedef __attribute__((ext_vector_type(4))) float f32x4;

__device__ __forceinline__ unsigned short f2bf(float f) {
  unsigned int u = __builtin_bit_cast(unsigned int, f);
  u += 0x7fff + ((u >> 16) & 1);      // RNE
  return (unsigned short)(u >> 16);
}
__device__ __forceinline__ float bf2f(unsigned short h) {
  unsigned int u = ((unsigned int)h) << 16;
  return __builtin_bit_cast(float, u);
}

// ---- workspace layout (bf16 elements), per layer ----
// W1T [256][512]  @ 0        (Wt[n][k] = W[k][n])
// UT  [ 64][512]  @ 131072
// W2ST[4096][256] @ 163840   (W2ST[64k+j][t] = W2[t][512+64k+j])
// W2bT[ 512][256] @ 1212416  (W2bT[n][t] = W2[t][n])
// VT  [ 512][ 64] @ 1343488
#define L_ELEMS 1376256

struct PrepParams {
  const float* W1[3]; const float* U[3]; const float* W2[3]; const float* V[3];
  short* ws;
};

__global__ __launch_bounds__(256) void prep_weights(PrepParams p) {
  const int y = blockIdx.y;           // 0..14
  const int l = y / 5, m = y - 5 * l;
  short* wsl = p.ws + (size_t)l * L_ELEMS;
  const float* in; short* out; int K, N, istride, ioff, kshift;
  switch (m) {
    case 0: in = p.W1[l]; out = wsl;           K = 512; N = 256;  istride = 256;  ioff = 0;   kshift = 9; break;
    case 1: in = p.U[l];  out = wsl + 131072;  K = 512; N = 64;   istride = 64;   ioff = 0;   kshift = 9; break;
    case 2: in = p.W2[l]; out = wsl + 163840;  K = 256; N = 4096; istride = 4608; ioff = 512; kshift = 8; break;
    case 3: in = p.W2[l]; out = wsl + 1212416; K = 256; N = 512;  istride = 4608; ioff = 0;   kshift = 8; break;
    default:in = p.V[l];  out = wsl + 1343488; K = 64;  N = 512;  istride = 512;  ioff = 0;   kshift = 6; break;
  }
  const long total = (long)K * N;
  for (long e = (long)blockIdx.x * 256 + threadIdx.x; e < total;
       e += (long)gridDim.x * 256) {
    const int k = (int)(e & (K - 1));
    const int n = (int)(e >> kshift);
    out[e] = (short)f2bf(in[(size_t)k * istride + ioff + n]);
  }
}

struct Params {
  const float* x;
  const float* b1[3];
  const float* b2[3];
  const float* Wout;
  const float* bout;
  const short* ws;
  float* out;
};

#define XP 520   // xs pitch in shorts (16B-aligned rows)
#define HP 264
#define TP 72

__global__ __launch_bounds__(NT, 4) void apg_mfma(Params p) {
  __shared__ short xs[R_T][XP];     // 16.6 KB  current layer input, bf16
  __shared__ short h1s[R_T][HP];    //  8.4 KB
  __shared__ short tmps[R_T][TP];   //  2.3 KB
  __shared__ float hs[R_T][68];     //  4.3 KB  h = x@U, f32
  __shared__ float tpart[R_T][64];  //  4.0 KB  stage-C k-lo partial sums

  const int tid = threadIdx.x;
  const int row0 = blockIdx.x * R_T;
  const int w   = tid >> 6;          // wave 0..7
  const int l15 = tid & 15;          // lane & 15
  const int g   = (tid & 63) >> 4;   // 0..3, wave-uniform groups
  const int koff = g * 8;

  // ---- load x tile -> bf16 LDS ----
  {
    const float4* xg = (const float4*)(p.x + (size_t)row0 * D_N);
    for (int i = tid; i < R_T * D_N / 4; i += NT) {
      float4 v = xg[i];
      const int r = i >> 7;
      const int c = (i & 127) << 2;
      short4v s4 = { (short)f2bf(v.x), (short)f2bf(v.y), (short)f2bf(v.z), (short)f2bf(v.w) };
      *(short4v*)&xs[r][c] = s4;
    }
  }
  __syncthreads();

  for (int l = 0; l < 3; ++l) {
    const short* wsl  = p.ws + (size_t)l * L_ELEMS;
    const short* W1T  = wsl;
    const short* UT   = wsl + 131072;
    const short* W2ST = wsl + 163840;
    const short* W2bT = wsl + 1212416;
    const short* VT   = wsl + 1343488;
    const float* b1 = p.b1[l];
    const float* b2 = p.b2[l];

    // ---- stage A: h1 = relu(x @ W1 + b1); wave w -> n in [32w, 32w+32) ----
    for (int nf = 0; nf < 2; ++nf) {
      const int n0 = (w << 5) + (nf << 4);
      const short* pb = W1T + ((size_t)(n0 + l15) << 9) + koff;
      short8 bf[16];
#pragma unroll
      for (int kk = 0; kk < 16; ++kk) bf[kk] = *(const short8*)(pb + kk * 32);
      f32x4 acc = {0.f, 0.f, 0.f, 0.f};
#pragma unroll
      for (int kk = 0; kk < 16; ++kk) {
        short8 a = *(const short8*)&xs[l15][kk * 32 + koff];
        acc = __builtin_amdgcn_mfma_f32_16x16x32_bf16(a, bf[kk], acc, 0, 0, 0);
      }
      const float bb = b1[n0 + l15];
#pragma unroll
      for (int i = 0; i < 4; ++i)
        h1s[g * 4 + i][n0 + l15] = (short)f2bf(fmaxf(acc[i] + bb, 0.f));
    }

    // ---- stage B: h = x @ U (f32, no relu); waves 0..3 only ----
    if (w < 4) {
      const int n0 = w << 4;
      const short* pb = UT + ((size_t)(n0 + l15) << 9) + koff;
      short8 bf[16];
#pragma unroll
      for (int kk = 0; kk < 16; ++kk) bf[kk] = *(const short8*)(pb + kk * 32);
      f32x4 acc = {0.f, 0.f, 0.f, 0.f};
#pragma unroll
      for (int kk = 0; kk < 16; ++kk) {
        short8 a = *(const short8*)&xs[l15][kk * 32 + koff];
        acc = __builtin_amdgcn_mfma_f32_16x16x32_bf16(a, bf[kk], acc, 0, 0, 0);
      }
#pragma unroll
      for (int i = 0; i < 4; ++i) hs[g * 4 + i][n0 + l15] = acc[i];
    }
    __syncthreads();

    // ---- stage C: tmp[r][j] = sum_k h[r,k] * (h1@W2S + b2S)[r, 64k+j]
    //      8 waves: (w&3) -> j-frag, (w>>2) -> k-half; LDS combine ----
    {
      const int j0 = (w & 3) << 4;
      const int kh = w >> 2;
      const int k0 = kh << 5;
      const int kend = k0 + 32;
      const short* pB = W2ST + ((size_t)(j0 + l15) << 8) + koff;
      const float* pb2 = b2 + D_N + j0 + l15;
      short8 bA[8], bB[8];
      {
        const short* pk = pB + ((size_t)k0 << 14);
#pragma unroll
        for (int kk = 0; kk < 8; ++kk) bA[kk] = *(const short8*)(pk + kk * 32);
      }
      float b2A = pb2[k0 << 6], b2B;
      short8 aH[8];
#pragma unroll
      for (int kk = 0; kk < 8; ++kk) aH[kk] = *(const short8*)&h1s[l15][kk * 32 + koff];
      float tacc[4] = {0.f, 0.f, 0.f, 0.f};
#pragma unroll 1
      for (int k = k0; k < kend; k += 2) {
        {
          const short* pk = pB + ((size_t)(k + 1) << 14);
#pragma unroll
          for (int kk = 0; kk < 8; ++kk) bB[kk] = *(const short8*)(pk + kk * 32);
          b2B = pb2[(k + 1) << 6];
          f32x4 s = {0.f, 0.f, 0.f, 0.f};
#pragma unroll
          for (int kk = 0; kk < 8; ++kk)
            s = __builtin_amdgcn_mfma_f32_16x16x32_bf16(aH[kk], bA[kk], s, 0, 0, 0);
#pragma unroll
          for (int i = 0; i < 4; ++i) tacc[i] += hs[g * 4 + i][k] * (s[i] + b2A);
        }
        {
          const int k2 = (k + 2 < kend) ? (k + 2) : (kend - 1);  // tail: redundant load
          const short* pk = pB + ((size_t)k2 << 14);
#pragma unroll
          for (int kk = 0; kk < 8; ++kk) bA[kk] = *(const short8*)(pk + kk * 32);
          b2A = pb2[k2 << 6];
          f32x4 s = {0.f, 0.f, 0.f, 0.f};
#pragma unroll
          for (int kk = 0; kk < 8; ++kk)
            s = __builtin_amdgcn_mfma_f32_16x16x32_bf16(aH[kk], bB[kk], s, 0, 0, 0);
#pragma unroll
          for (int i = 0; i < 4; ++i) tacc[i] += hs[g * 4 + i][k + 1] * (s[i] + b2B);
        }
      }
      if (kh == 0) {
#pragma unroll
        for (int i = 0; i < 4; ++i) tpart[g * 4 + i][j0 + l15] = tacc[i];
      }
      __syncthreads();
      if (kh == 1) {
#pragma unroll
        for (int i = 0; i < 4; ++i)
          tmps[g * 4 + i][j0 + l15] =
              (short)f2bf(tpart[g * 4 + i][j0 + l15] + tacc[i]);
      }
    }
    __syncthreads();

    // ---- stage D: xnew = relu(tmp@V + h1@W2[:, :512] + b2[:512]) -> xs ----
    {
      short8 aT[2], aD[8];
#pragma unroll
      for (int kk = 0; kk < 2; ++kk) aT[kk] = *(const short8*)&tmps[l15][kk * 32 + koff];
#pragma unroll
      for (int kk = 0; kk < 8; ++kk) aD[kk] = *(const short8*)&h1s[l15][kk * 32 + koff];
      for (int nb = 0; nb < 4; ++nb) {
        const int n0 = ((nb << 3) + w) << 4;   // 8 waves interleave over 32 n-frags
        const short* pv = VT + ((size_t)(n0 + l15) << 6) + koff;
        const short* pw = W2bT + ((size_t)(n0 + l15) << 8) + koff;
        short8 bv[2], bw[8];
#pragma unroll
        for (int kk = 0; kk < 2; ++kk) bv[kk] = *(const short8*)(pv + kk * 32);
#pragma unroll
        for (int kk = 0; kk < 8; ++kk) bw[kk] = *(const short8*)(pw + kk * 32);
        f32x4 acc = {0.f, 0.f, 0.f, 0.f};
#pragma unroll
        for (int kk = 0; kk < 2; ++kk)
          acc = __builtin_amdgcn_mfma_f32_16x16x32_bf16(aT[kk], bv[kk], acc, 0, 0, 0);
#pragma unroll
        for (int kk = 0; kk < 8; ++kk)
          acc = __builtin_amdgcn_mfma_f32_16x16x32_bf16(aD[kk], bw[kk], acc, 0, 0, 0);
        const float bb = b2[n0 + l15];
#pragma unroll
        for (int i = 0; i < 4; ++i)
          xs[g * 4 + i][n0 + l15] = (short)f2bf(fmaxf(acc[i] + bb, 0.f));
      }
    }
    __syncthreads();
  }

  // ---- out = x @ Wout + bout (threads 0..255) ----
  if (tid < 256) {
    const int r  = tid >> 4;
    const int cl = tid & 15;
    float acc = 0.f;
    for (int c = cl; c < D_N; c += 16)
      acc = fmaf(bf2f((unsigned short)xs[r][c]), p.Wout[c], acc);
#pragma unroll
    for (int s = 1; s < 16; s <<= 1) acc += __shfl_xor(acc, s, 64);
    if (cl == 0) p.out[row0 + r] = acc + p.bout[0];
  }
}

extern "C" void kernel_launch(void* const* d_in, const int* in_sizes, int n_in,
                              void* d_out, int out_size, void* d_ws, size_t ws_size,
                              hipStream_t stream) {
  (void)in_sizes; (void)n_in; (void)ws_size; (void)out_size;
  PrepParams pp;
  Params p;
  p.x = (const float*)d_in[0];
  for (int l = 0; l < 3; ++l) {
    const int base = 1 + l * 6;
    pp.U[l]  = (const float*)d_in[base + 0];
    pp.V[l]  = (const float*)d_in[base + 1];
    pp.W1[l] = (const float*)d_in[base + 2];
    p.b1[l]  = (const float*)d_in[base + 3];
    pp.W2[l] = (const float*)d_in[base + 4];
    p.b2[l]  = (const float*)d_in[base + 5];
  }
  p.Wout = (const float*)d_in[19];
  p.bout = (const float*)d_in[20];
  p.ws   = (const short*)d_ws;
  p.out  = (float*)d_out;
  pp.ws  = (short*)d_ws;

  hipLaunchKernelGGL(prep_weights, dim3(1024, 15), dim3(256), 0, stream, pp);
  hipLaunchKernelGGL(apg_mfma, dim3(B_N / R_T), dim3(NT), 0, stream, p);
}

// Round 5
// 322.907 us; speedup vs baseline: 1.5146x; 1.5146x over previous
//
#include <hip/hip_runtime.h>

#define B_N 8192
#define D_N 512
#define K_N 64
#define H_N 256
#define SC  4608   // K*K + D
#define R_T 32     // rows per block
#define NT  512    // 8 waves

typedef __attribute__((ext_vector_type(8))) short short8;
typedef __attribute__((ext_vector_type(4))) short short4v;
typedef __attribute__((ext_vector_type(4))) float f32x4;

__device__ __forceinline__ unsigned short f2bf(float f) {
  unsigned int u = __builtin_bit_cast(unsigned int, f);
  u += 0x7fff + ((u >> 16) & 1);      // RNE
  return (unsigned short)(u >> 16);
}
__device__ __forceinline__ float bf2f(unsigned short h) {
  unsigned int u = ((unsigned int)h) << 16;
  return __builtin_bit_cast(float, u);
}

// ---- workspace layout (bf16 elements), per layer ----
// W1T [256][512]  @ 0        (W1T[n][k] = W1[k][n])
// UT  [ 64][512]  @ 131072
// W2p [panelized] @ 163840   : idx = (((k*2+th)*16 + c)*64 + j)*8 + e
//                              value = W2[t][512+64k+j], t = th*128+(c>>2)*32+(c&3)*8+e
// W2bT[ 512][256] @ 1212416  (W2bT[n][t] = W2[t][n])
// VT  [ 512][ 64] @ 1343488
#define L_ELEMS 1376256

struct PrepParams {
  const float* W1[3]; const float* U[3]; const float* W2[3]; const float* V[3];
  short* ws;
};

__global__ __launch_bounds__(256) void prep_weights(PrepParams p) {
  const int y = blockIdx.y;           // 0..14
  const int l = y / 5, m = y - 5 * l;
  short* wsl = p.ws + (size_t)l * L_ELEMS;
  if (m == 2) {                       // W2p panelized
    const float* in = p.W2[l];
    short* out = wsl + 163840;
    const long total = 1048576;
    for (long e = (long)blockIdx.x * 256 + threadIdx.x; e < total;
         e += (long)gridDim.x * 256) {
      const int el = (int)(e & 7);
      const int j  = (int)((e >> 3) & 63);
      const int c  = (int)((e >> 9) & 15);
      const int th = (int)((e >> 13) & 1);
      const int k  = (int)(e >> 14);
      const int t  = th * 128 + (c >> 2) * 32 + (c & 3) * 8 + el;
      out[e] = (short)f2bf(in[(size_t)t * SC + 512 + 64 * k + j]);
    }
    return;
  }
  const float* in; short* out; int K, istride, ioff, kshift;
  switch (m) {
    case 0: in = p.W1[l]; out = wsl;           K = 512; istride = 256;  ioff = 0; kshift = 9; break;
    case 1: in = p.U[l];  out = wsl + 131072;  K = 512; istride = 64;   ioff = 0; kshift = 9; break;
    case 3: in = p.W2[l]; out = wsl + 1212416; K = 256; istride = 4608; ioff = 0; kshift = 8; break;
    default:in = p.V[l];  out = wsl + 1343488; K = 64;  istride = 512;  ioff = 0; kshift = 6; break;
  }
  const long total = (long)K * ((m == 0) ? 256 : (m == 1) ? 64 : (m == 3) ? 512 : 512);
  for (long e = (long)blockIdx.x * 256 + threadIdx.x; e < total;
       e += (long)gridDim.x * 256) {
    const int k = (int)(e & (K - 1));
    const int n = (int)(e >> kshift);
    out[e] = (short)f2bf(in[(size_t)k * istride + ioff + n]);
  }
}

struct Params {
  const float* x;
  const float* b1[3];
  const float* b2[3];
  const float* Wout;
  const float* bout;
  const short* ws;
  float* out;
};

#define XP 520   // xs pitch in shorts (rows 1040 B: 16B-aligned, banks spread)
#define HP 264
#define TP 72

__device__ __forceinline__ void stage_panel(const short* W2p, short* pan,
                                            int s, int b, int w, int lane) {
#pragma unroll
  for (int i = 0; i < 2; ++i) {
    const short* gp = W2p + ((size_t)s << 13) + (w << 10) + (i << 9) + (lane << 3);
    short* lp = pan + (b << 13) + (w << 10) + (i << 9);   // wave-uniform dest
    __builtin_amdgcn_global_load_lds(
        (const __attribute__((address_space(1))) void*)gp,
        (__attribute__((address_space(3))) void*)lp, 16, 0, 0);
  }
}

__global__ __launch_bounds__(NT, 2) void apg_mfma(Params p) {
  __shared__ __attribute__((aligned(16))) short xs[R_T][XP]; // 33.3 KB; doubles as stage-C panel dbuf
  __shared__ short h1s[R_T][HP];    // 16.9 KB
  __shared__ short tmps[R_T][TP];   //  4.6 KB
  __shared__ float hs[R_T][68];     //  8.7 KB  h = x@U, f32

  const int tid  = threadIdx.x;
  const int row0 = blockIdx.x * R_T;
  const int w    = tid >> 6;         // wave 0..7
  const int lane = tid & 63;
  const int l15  = tid & 15;
  const int g    = (tid & 63) >> 4;  // 0..3
  const int koff = g * 8;
  const int rh   = w >> 2;           // row-half 0/1
  const int rbase = rh * 16;

  // ---- load x tile -> bf16 LDS ----
  {
    const float4* xg = (const float4*)(p.x + (size_t)row0 * D_N);
    for (int i = tid; i < R_T * D_N / 4; i += NT) {
      float4 v = xg[i];
      const int r = i >> 7;
      const int c = (i & 127) << 2;
      short4v s4 = { (short)f2bf(v.x), (short)f2bf(v.y), (short)f2bf(v.z), (short)f2bf(v.w) };
      *(short4v*)&xs[r][c] = s4;
    }
  }
  __syncthreads();

  for (int l = 0; l < 3; ++l) {
    const short* wsl  = p.ws + (size_t)l * L_ELEMS;
    const short* W1T  = wsl;
    const short* UT   = wsl + 131072;
    const short* W2p  = wsl + 163840;
    const short* W2bT = wsl + 1212416;
    const short* VT   = wsl + 1343488;
    const float* b1 = p.b1[l];
    const float* b2 = p.b2[l];

    // ---- A-operand x fragments (rows rbase..rbase+16), kept for stages A+B ----
    short8 aX[16];
#pragma unroll
    for (int kk = 0; kk < 16; ++kk)
      aX[kk] = *(const short8*)&xs[rbase + l15][kk * 32 + koff];

    // ---- stage A: h1 = relu(x @ W1 + b1); wave -> 4 n-frags of its row-half ----
    for (int nf = 0; nf < 4; ++nf) {
      const int n0 = (((w & 3) << 2) + nf) << 4;
      const short* pb = W1T + ((size_t)(n0 + l15) << 9) + koff;
      short8 bf[16];
#pragma unroll
      for (int kk = 0; kk < 16; ++kk) bf[kk] = *(const short8*)(pb + kk * 32);
      f32x4 acc = {0.f, 0.f, 0.f, 0.f};
#pragma unroll
      for (int kk = 0; kk < 16; ++kk)
        acc = __builtin_amdgcn_mfma_f32_16x16x32_bf16(aX[kk], bf[kk], acc, 0, 0, 0);
      const float bb = b1[n0 + l15];
#pragma unroll
      for (int i = 0; i < 4; ++i)
        h1s[rbase + g * 4 + i][n0 + l15] = (short)f2bf(fmaxf(acc[i] + bb, 0.f));
    }

    // ---- stage B: h = x @ U (f32); wave -> n-frag (w&3), its row-half ----
    {
      const int n0 = (w & 3) << 4;
      const short* pb = UT + ((size_t)(n0 + l15) << 9) + koff;
      short8 bf[16];
#pragma unroll
      for (int kk = 0; kk < 16; ++kk) bf[kk] = *(const short8*)(pb + kk * 32);
      f32x4 acc = {0.f, 0.f, 0.f, 0.f};
#pragma unroll
      for (int kk = 0; kk < 16; ++kk)
        acc = __builtin_amdgcn_mfma_f32_16x16x32_bf16(aX[kk], bf[kk], acc, 0, 0, 0);
#pragma unroll
      for (int i = 0; i < 4; ++i) hs[rbase + g * 4 + i][n0 + l15] = acc[i];
    }
    __syncthreads();   // h1s, hs ready; xs now dead -> becomes panel dbuf

    // ---- stage C: tmp[r][j] = sum_k h[r,k] * (h1@W2S + b2S)[r, 64k+j] ----
    // W2S streamed as 128 16KB panels (k x t-half) via global_load_lds, dbuf in xs.
    {
      const int j0 = (w & 3) << 4;
      short* pan = &xs[0][0];
      short8 aH[8];
#pragma unroll
      for (int kk = 0; kk < 8; ++kk)
        aH[kk] = *(const short8*)&h1s[rbase + l15][kk * 32 + koff];
      const float* pb2 = b2 + D_N + j0 + l15;
      float tacc[4] = {0.f, 0.f, 0.f, 0.f};

      stage_panel(W2p, pan, 0, 0, w, lane);
      __syncthreads();               // panel 0 staged (compiler drains vmcnt)

#pragma unroll 1
      for (int k = 0; k < K_N; ++k) {
        // even phase: panel (2k) in buf0; prefetch panel 2k+1 -> buf1
        stage_panel(W2p, pan, 2 * k + 1, 1, w, lane);
        const float b2v = pb2[k << 6];
        f32x4 sacc = {0.f, 0.f, 0.f, 0.f};
#pragma unroll
        for (int kkl = 0; kkl < 4; ++kkl) {
          short8 bfrag = *(const short8*)(pan + ((kkl * 4 + g) << 9) + ((j0 + l15) << 3));
          sacc = __builtin_amdgcn_mfma_f32_16x16x32_bf16(aH[kkl], bfrag, sacc, 0, 0, 0);
        }
        __syncthreads();             // panel 2k+1 staged; buf0 reads done
        // odd phase: panel (2k+1) in buf1; prefetch panel 2k+2 -> buf0
        if (k + 1 < K_N) stage_panel(W2p, pan, 2 * k + 2, 0, w, lane);
#pragma unroll
        for (int kkl = 0; kkl < 4; ++kkl) {
          short8 bfrag = *(const short8*)(pan + 8192 + ((kkl * 4 + g) << 9) + ((j0 + l15) << 3));
          sacc = __builtin_amdgcn_mfma_f32_16x16x32_bf16(aH[4 + kkl], bfrag, sacc, 0, 0, 0);
        }
#pragma unroll
        for (int i = 0; i < 4; ++i)
          tacc[i] += hs[rbase + g * 4 + i][k] * (sacc[i] + b2v);
        __syncthreads();             // panel 2k+2 staged; buf1 reads done
      }
#pragma unroll
      for (int i = 0; i < 4; ++i)
        tmps[rbase + g * 4 + i][j0 + l15] = (short)f2bf(tacc[i]);
    }
    __syncthreads();

    // ---- stage D: xnew = relu(tmp@V + h1@W2[:, :512] + b2[:512]) -> xs ----
    {
      short8 aT[2], aD[8];
#pragma unroll
      for (int kk = 0; kk < 2; ++kk)
        aT[kk] = *(const short8*)&tmps[rbase + l15][kk * 32 + koff];
#pragma unroll
      for (int kk = 0; kk < 8; ++kk)
        aD[kk] = *(const short8*)&h1s[rbase + l15][kk * 32 + koff];
      for (int ti = 0; ti < 8; ++ti) {
        const int n0 = ((ti << 2) + (w & 3)) << 4;
        const short* pv = VT + ((size_t)(n0 + l15) << 6) + koff;
        const short* pw = W2bT + ((size_t)(n0 + l15) << 8) + koff;
        short8 bv[2], bw[8];
#pragma unroll
        for (int kk = 0; kk < 2; ++kk) bv[kk] = *(const short8*)(pv + kk * 32);
#pragma unroll
        for (int kk = 0; kk < 8; ++kk) bw[kk] = *(const short8*)(pw + kk * 32);
        f32x4 acc = {0.f, 0.f, 0.f, 0.f};
#pragma unroll
        for (int kk = 0; kk < 2; ++kk)
          acc = __builtin_amdgcn_mfma_f32_16x16x32_bf16(aT[kk], bv[kk], acc, 0, 0, 0);
#pragma unroll
        for (int kk = 0; kk < 8; ++kk)
          acc = __builtin_amdgcn_mfma_f32_16x16x32_bf16(aD[kk], bw[kk], acc, 0, 0, 0);
        const float bb = b2[n0 + l15];
#pragma unroll
        for (int i = 0; i < 4; ++i)
          xs[rbase + g * 4 + i][n0 + l15] = (short)f2bf(fmaxf(acc[i] + bb, 0.f));
      }
    }
    __syncthreads();
  }

  // ---- out = x @ Wout + bout ----
  {
    const int r  = tid >> 4;
    const int cl = tid & 15;
    float acc = 0.f;
    for (int c = cl; c < D_N; c += 16)
      acc = fmaf(bf2f((unsigned short)xs[r][c]), p.Wout[c], acc);
#pragma unroll
    for (int s = 1; s < 16; s <<= 1) acc += __shfl_xor(acc, s, 64);
    if (cl == 0) p.out[row0 + r] = acc + p.bout[0];
  }
}

extern "C" void kernel_launch(void* const* d_in, const int* in_sizes, int n_in,
                              void* d_out, int out_size, void* d_ws, size_t ws_size,
                              hipStream_t stream) {
  (void)in_sizes; (void)n_in; (void)ws_size; (void)out_size;
  PrepParams pp;
  Params p;
  p.x = (const float*)d_in[0];
  for (int l = 0; l < 3; ++l) {
    const int base = 1 + l * 6;
    pp.U[l]  = (const float*)d_in[base + 0];
    pp.V[l]  = (const float*)d_in[base + 1];
    pp.W1[l] = (const float*)d_in[base + 2];
    p.b1[l]  = (const float*)d_in[base + 3];
    pp.W2[l] = (const float*)d_in[base + 4];
    p.b2[l]  = (const float*)d_in[base + 5];
  }
  p.Wout = (const float*)d_in[19];
  p.bout = (const float*)d_in[20];
  p.ws   = (const short*)d_ws;
  p.out  = (float*)d_out;
  pp.ws  = (short*)d_ws;

  hipLaunchKernelGGL(prep_weights, dim3(1024, 15), dim3(256), 0, stream, pp);
  hipLaunchKernelGGL(apg_mfma, dim3(B_N / R_T), dim3(NT), 0, stream, p);
}